// Round 7
// baseline (18.362 us; speedup 1.0000x reference)
//
#include <hip/hip_runtime.h>

#define RPB 64              // residues per block (one per lane, 4 specialized waves)
#define FRS 18              // LDS floats per frame (16 + 2 pad) -> bank spread, 8B aligned
#define RSS (9*FRS)         // 162 floats per residue

// ---------- helpers ----------

__device__ __forceinline__ float rsqz(float d) { return rsqrtf(fmaxf(d, 1e-24f)); }

__device__ __forceinline__ void angNorm(float x, float y, float& c, float& s) {
    float inv = rsqz(x*x + y*y);
    c = x * inv; s = y * inv;
}

__device__ __forceinline__ void loadMat4(const float* __restrict__ p, float B[4][4]) {
    const float4* q4 = reinterpret_cast<const float4*>(p);
#pragma unroll
    for (int i = 0; i < 4; ++i) {
        float4 r = q4[i];
        B[i][0]=r.x; B[i][1]=r.y; B[i][2]=r.z; B[i][3]=r.w;
    }
}

__device__ __forceinline__ void storeRowLDS(float* dst, float a, float b, float c, float d) {
    *reinterpret_cast<float2*>(dst)     = make_float2(a, b);
    *reinterpret_cast<float2*>(dst + 2) = make_float2(c, d);
}

__device__ __forceinline__ void storeMatLDS(float* dst, const float M[4][4]) {
#pragma unroll
    for (int i = 0; i < 4; ++i)
        storeRowLDS(dst + i*4, M[i][0], M[i][1], M[i][2], M[i][3]);
}

__device__ __forceinline__ void storeAffineLDS(float* dst, const float f[3][4]) {
#pragma unroll
    for (int i = 0; i < 3; ++i)
        storeRowLDS(dst + i*4, f[i][0], f[i][1], f[i][2], f[i][3]);
    storeRowLDS(dst + 12, 0.f, 0.f, 0.f, 1.f);
}

// global frame stores straight from registers (regular stores; L2 write-combines)
__device__ __forceinline__ void storeMatG(float* dst, const float M[4][4]) {
    float4* g = reinterpret_cast<float4*>(dst);
#pragma unroll
    for (int i = 0; i < 4; ++i)
        g[i] = make_float4(M[i][0], M[i][1], M[i][2], M[i][3]);
}

__device__ __forceinline__ void storeAffineG(float* dst, const float f[3][4]) {
    float4* g = reinterpret_cast<float4*>(dst);
#pragma unroll
    for (int i = 0; i < 3; ++i)
        g[i] = make_float4(f[i][0], f[i][1], f[i][2], f[i][3]);
    g[3] = make_float4(0.f, 0.f, 0.f, 1.f);
}

// C = A * B, A affine as 3 rows of 4 (row3 implicitly [0,0,0,1]); C row3 = B row3
__device__ __forceinline__ void affineMul(const float a[3][4], const float B[4][4], float C[4][4]) {
#pragma unroll
    for (int i = 0; i < 3; ++i)
#pragma unroll
        for (int j = 0; j < 4; ++j)
            C[i][j] = a[i][0]*B[0][j] + a[i][1]*B[1][j] + a[i][2]*B[2][j] + a[i][3]*B[3][j];
#pragma unroll
    for (int j = 0; j < 4; ++j) C[3][j] = B[3][j];
}

__device__ __forceinline__ void mat4Mul(const float A[4][4], const float B[4][4], float C[4][4]) {
#pragma unroll
    for (int i = 0; i < 4; ++i)
#pragma unroll
        for (int j = 0; j < 4; ++j)
            C[i][j] = A[i][0]*B[0][j] + A[i][1]*B[1][j] + A[i][2]*B[2][j] + A[i][3]*B[3][j];
}

// M = M @ rotX(c,s): only columns 1,2 change
__device__ __forceinline__ void postRotX(float M[4][4], float c, float s) {
#pragma unroll
    for (int i = 0; i < 4; ++i) {
        float m1 = M[i][1], m2 = M[i][2];
        M[i][1] = c*m1 + s*m2;
        M[i][2] = c*m2 - s*m1;
    }
}

__device__ __forceinline__ void rotAxis3(float G[3][3], float c, float s,
                                         float u0, float u1, float u2) {
    float omc = 1.0f - c;
    G[0][0] = c + u0*u0*omc;    G[0][1] = u0*u1*omc - u2*s; G[0][2] = u0*u2*omc + u1*s;
    G[1][0] = u0*u1*omc + u2*s; G[1][1] = c + u1*u1*omc;    G[1][2] = u1*u2*omc - u0*s;
    G[2][0] = u0*u2*omc - u1*s; G[2][1] = u1*u2*omc + u0*s; G[2][2] = c + u2*u2*omc;
}

__device__ __forceinline__ void mat3Mul(const float A[3][3], const float B[3][3], float C[3][3]) {
#pragma unroll
    for (int i = 0; i < 3; ++i)
#pragma unroll
        for (int j = 0; j < 3; ++j)
            C[i][j] = A[i][0]*B[0][j] + A[i][1]*B[1][j] + A[i][2]*B[2][j];
}

// rigid_from_3_points -> affine rows {R | T}, R columns are e1,e2,e3
__device__ __forceinline__ void computeF0(const float* __restrict__ xyz, int t, float f0[3][4]) {
    const float* p = xyz + (size_t)t * 9;
    float N0=p[0], N1=p[1], N2=p[2];
    float A0=p[3], A1=p[4], A2=p[5];
    float C0=p[6], C1=p[7], C2=p[8];

    float v10=C0-A0, v11=C1-A1, v12=C2-A2;
    float v20=N0-A0, v21=N1-A1, v22=N2-A2;
    float i1 = rsqz(v10*v10 + v11*v11 + v12*v12);
    float e10=v10*i1, e11=v11*i1, e12=v12*i1;
    float d  = e10*v20 + e11*v21 + e12*v22;
    float u20=v20-e10*d, u21=v21-e11*d, u22=v22-e12*d;
    float i2 = rsqz(u20*u20 + u21*u21 + u22*u22);
    float e20=u20*i2, e21=u21*i2, e22=u22*i2;
    float e30=e11*e22 - e12*e21;
    float e31=e12*e20 - e10*e22;
    float e32=e10*e21 - e11*e20;

    f0[0][0]=e10; f0[0][1]=e20; f0[0][2]=e30; f0[0][3]=A0;
    f0[1][0]=e11; f0[1][1]=e21; f0[1][2]=e31; f0[1][3]=A1;
    f0[2][0]=e12; f0[2][1]=e22; f0[2][2]=e32; f0[2][3]=A2;
}

// ---------------------------- fused kernel ----------------------------
// 256 threads = 4 waves, 64 residues/block. Wave specialization:
//  wv0: F0, F1     wv1: F2, F3     wv2: axes + F8
//  wv3: P4..P7 suffix chain (registers); after barrier reads F8, emits F4..F7
// Frames stored to global FROM REGISTERS at production point (overlaps compute)
// and to LDS for the atom gather. Final phase: one atom per lane, 9 iterations.

__global__ __launch_bounds__(256, 3) void fused_kernel(
    const int*   __restrict__ seq,     // (BL)
    const float* __restrict__ xyz,     // (BL,3,3)
    const float* __restrict__ alphas,  // (BL,10,2)
    const int*   __restrict__ bidx,    // (NAA,36)
    const float* __restrict__ RTs,     // (NAA,7,4,4)
    const float* __restrict__ xibf,    // (NAA,36,4)
    float*       __restrict__ out_fr,  // (BL,9,4,4)
    float*       __restrict__ out_xyz, // (BL,36,3)
    int BL)
{
    __shared__ float lds_fr[RPB * RSS];
    __shared__ int   lds_seq[RPB];

    const int tid  = threadIdx.x;
    const int wv   = tid >> 6;
    const int r    = tid & 63;
    const int base = blockIdx.x * RPB;
    const int t    = base + r;
    const bool valid = (t < BL);

    int s = 0;
    if (valid) s = seq[t];
    const float* rb = RTs + (size_t)s * 112;
    const float* al = alphas + (size_t)t * 20;
    float* fl = lds_fr + r * RSS;
    float* fg = out_fr + (size_t)t * 144;

    // registers carried across barrier 1 (wave 3)
    float P4[4][4], P5[4][4], P6[4][4], P7[4][4];

    if (valid) {
        if (wv == 0) {
            lds_seq[r] = s;
            float f0[3][4]; computeF0(xyz, t, f0);
            storeAffineLDS(fl, f0);
            storeAffineG(fg, f0);

            float2 a0 = *reinterpret_cast<const float2*>(al + 0);
            float c0, s0; angNorm(a0.x, a0.y, c0, s0);
            float B[4][4], F[4][4];
            loadMat4(rb + 0, B);
            affineMul(f0, B, F); postRotX(F, c0, s0);
            storeMatLDS(fl + 1*FRS, F);
            storeMatG(fg + 16, F);
        } else if (wv == 1) {
            float f0[3][4]; computeF0(xyz, t, f0);
            float2 a1 = *reinterpret_cast<const float2*>(al + 2);
            float2 a2 = *reinterpret_cast<const float2*>(al + 4);
            float c, sn;
            float B[4][4], F[4][4];
            angNorm(a1.x, a1.y, c, sn);
            loadMat4(rb + 16, B); affineMul(f0, B, F); postRotX(F, c, sn);
            storeMatLDS(fl + 2*FRS, F);
            storeMatG(fg + 32, F);
            angNorm(a2.x, a2.y, c, sn);
            loadMat4(rb + 32, B); affineMul(f0, B, F); postRotX(F, c, sn);
            storeMatLDS(fl + 3*FRS, F);
            storeMatG(fg + 48, F);
        } else if (wv == 2) {
            float f0[3][4]; computeF0(xyz, t, f0);
            // CB rotation axes from base geometry
            const float* bxp = xibf + (size_t)s * 144;
            float4 b0 = reinterpret_cast<const float4*>(bxp)[0];
            float4 b1 = reinterpret_cast<const float4*>(bxp)[1];
            float4 b2 = reinterpret_cast<const float4*>(bxp)[2];
            float4 b4 = reinterpret_cast<const float4*>(bxp)[4];

            float NCr0 = 0.5f*(b2.x + b0.x), NCr1 = 0.5f*(b2.y + b0.y), NCr2 = 0.5f*(b2.z + b0.z);
            float ba0 = b4.x - b1.x, ba1 = b4.y - b1.y, ba2 = b4.z - b1.z;
            float w0 = NCr0 - b1.x, w1 = NCr1 - b1.y, w2 = NCr2 - b1.z;
            float x10 = ba1*w2 - ba2*w1, x11 = ba2*w0 - ba0*w2, x12 = ba0*w1 - ba1*w0;
            float in1 = rsqz(x10*x10 + x11*x11 + x12*x12);
            x10 *= in1; x11 *= in1; x12 *= in1;
            float NCp0 = b2.x - b0.x, NCp1 = b2.y - b0.y, NCp2 = b2.z - b0.z;
            float dp = NCp0*NCr0 + NCp1*NCr1 + NCp2*NCr2;
            float dr = NCr0*NCr0 + NCr1*NCr1 + NCr2*NCr2;
            float sf = dp / dr;
            float q0 = NCp0 - sf*NCr0, q1 = NCp1 - sf*NCr1, q2 = NCp2 - sf*NCr2;
            float x20 = ba1*q2 - ba2*q1, x21 = ba2*q0 - ba0*q2, x22 = ba0*q1 - ba1*q0;
            float in2 = rsqz(x20*x20 + x21*x21 + x22*x22);
            x20 *= in2; x21 *= in2; x22 *= in2;

            float2 a7 = *reinterpret_cast<const float2*>(al + 14);
            float2 a8 = *reinterpret_cast<const float2*>(al + 16);
            float c7, s7, c8, s8;
            angNorm(a7.x, a7.y, c7, s7);
            angNorm(a8.x, a8.y, c8, s8);
            float G1[3][3], G2[3][3], G12[3][3], R8[3][3];
            rotAxis3(G1, c7, s7, x10, x11, x12);
            rotAxis3(G2, c8, s8, x20, x21, x22);
            mat3Mul(G1, G2, G12);
            float R0[3][3] = { {f0[0][0],f0[0][1],f0[0][2]},
                               {f0[1][0],f0[1][1],f0[1][2]},
                               {f0[2][0],f0[2][1],f0[2][2]} };
            mat3Mul(R0, G12, R8);
            float f8[3][4];
#pragma unroll
            for (int i = 0; i < 3; ++i) {
                f8[i][0] = R8[i][0]; f8[i][1] = R8[i][1]; f8[i][2] = R8[i][2];
                f8[i][3] = f0[i][3];
            }
            storeAffineLDS(fl + 8*FRS, f8);
            storeAffineG(fg + 128, f8);
        } else {
            // wv == 3: suffix chain in base coordinates, kept in registers
            float2 a3 = *reinterpret_cast<const float2*>(al + 6);
            float2 a4 = *reinterpret_cast<const float2*>(al + 8);
            float2 a5 = *reinterpret_cast<const float2*>(al + 10);
            float2 a6 = *reinterpret_cast<const float2*>(al + 12);
            float2 a9 = *reinterpret_cast<const float2*>(al + 18);
            float c3,s3, c4,s4, c5,s5, c6,s6, c9,s9;
            angNorm(a3.x, a3.y, c3, s3);
            angNorm(a4.x, a4.y, c4, s4);
            angNorm(a5.x, a5.y, c5, s5);
            angNorm(a6.x, a6.y, c6, s6);
            angNorm(a9.x, a9.y, c9, s9);

            // M = rotX(c3,s3) @ rotZ(c9,s9), 3x3
            float M00 = c9,    M01 = -s9;
            float M10 = c3*s9, M11 = c3*c9, M12 = -s3;
            float M20 = s3*s9, M21 = s3*c9, M22 = c3;

            float B[4][4];
            loadMat4(rb + 48, B);
#pragma unroll
            for (int i = 0; i < 4; ++i) {
                P4[i][0] = B[i][0]*M00 + B[i][1]*M10 + B[i][2]*M20;
                P4[i][1] = B[i][0]*M01 + B[i][1]*M11 + B[i][2]*M21;
                P4[i][2] =               B[i][1]*M12 + B[i][2]*M22;
                P4[i][3] = B[i][3];
            }
            loadMat4(rb + 64, B); mat4Mul(P4, B, P5); postRotX(P5, c4, s4);
            loadMat4(rb + 80, B); mat4Mul(P5, B, P6); postRotX(P6, c5, s5);
            loadMat4(rb + 96, B); mat4Mul(P6, B, P7); postRotX(P7, c6, s6);
        }
    }
    __syncthreads();

    if (valid && wv == 3) {
        // read F8 rotation+translation written by wave 2
        float f8b[3][4];
        const float* qp = fl + 8*FRS;
#pragma unroll
        for (int i = 0; i < 3; ++i) {
            float2 u = *reinterpret_cast<const float2*>(qp + i*4);
            float2 w = *reinterpret_cast<const float2*>(qp + i*4 + 2);
            f8b[i][0]=u.x; f8b[i][1]=u.y; f8b[i][2]=w.x; f8b[i][3]=w.y;
        }
        float F[4][4];
        affineMul(f8b, P4, F); storeMatLDS(fl + 4*FRS, F); storeMatG(fg + 64, F);
        affineMul(f8b, P5, F); storeMatLDS(fl + 5*FRS, F); storeMatG(fg + 80, F);
        affineMul(f8b, P6, F); storeMatLDS(fl + 6*FRS, F); storeMatG(fg + 96, F);
        affineMul(f8b, P7, F); storeMatLDS(fl + 7*FRS, F); storeMatG(fg + 112, F);
    }
    __syncthreads();

    // atom phase: one atom per lane, RPB*36 = 2304 = 9*256 dense iterations
#pragma unroll
    for (int k = 0; k < 9; ++k) {
        int c = tid + k*256;
        int res = c / 36;
        int a = c - res*36;
        int tt = base + res;
        if (tt < BL) {
            int ss  = lds_seq[res];
            int idx = bidx[ss*36 + a];
            float4 v = *reinterpret_cast<const float4*>(xibf + ((size_t)ss*36 + a)*4);
            const float* fp = lds_fr + res*RSS + idx*FRS;
            float2 r00 = *reinterpret_cast<const float2*>(fp + 0);
            float2 r01 = *reinterpret_cast<const float2*>(fp + 2);
            float2 r10 = *reinterpret_cast<const float2*>(fp + 4);
            float2 r11 = *reinterpret_cast<const float2*>(fp + 6);
            float2 r20 = *reinterpret_cast<const float2*>(fp + 8);
            float2 r21 = *reinterpret_cast<const float2*>(fp + 10);
            float x = r00.x*v.x + r00.y*v.y + r01.x*v.z + r01.y*v.w;
            float y = r10.x*v.x + r10.y*v.y + r11.x*v.z + r11.y*v.w;
            float z = r20.x*v.x + r20.y*v.y + r21.x*v.z + r21.y*v.w;
            size_t o = (size_t)base*108 + (size_t)c*3;
            out_xyz[o+0] = x;
            out_xyz[o+1] = y;
            out_xyz[o+2] = z;
        }
    }
}

// ---------------------------- launch ----------------------------

extern "C" void kernel_launch(void* const* d_in, const int* in_sizes, int n_in,
                              void* d_out, int out_size, void* d_ws, size_t ws_size,
                              hipStream_t stream) {
    const int*   seq    = (const int*)  d_in[0];
    const float* xyz    = (const float*)d_in[1];
    const float* alphas = (const float*)d_in[2];
    const int*   bidx   = (const int*)  d_in[3];
    const float* RTs    = (const float*)d_in[4];
    const float* xibf   = (const float*)d_in[5];
    float*       out    = (float*)d_out;

    int BL = in_sizes[0];                       // B * L
    float* out_xyz = out + (size_t)BL * 144;

    int blocks = (BL + RPB - 1) / RPB;
    fused_kernel<<<blocks, 256, 0, stream>>>(seq, xyz, alphas, bidx, RTs, xibf,
                                             out, out_xyz, BL);
}

// Round 8
// 14.532 us; speedup vs baseline: 1.2636x; 1.2636x over previous
//
#include <hip/hip_runtime.h>

#define RPB 64              // residues per block (4 lanes per residue, 16 residues per wave)
#define FRS 20              // LDS floats per frame (16 + 4 pad) -> 16B-aligned rows, bank spread
#define RSS (9*FRS)         // 180 floats per residue (720B, 16B-aligned)

// ---------- helpers ----------

__device__ __forceinline__ float rsqz(float d) { return rsqrtf(fmaxf(d, 1e-24f)); }

__device__ __forceinline__ void angNorm(float x, float y, float& c, float& s) {
    float inv = rsqz(x*x + y*y);
    c = x * inv; s = y * inv;
}

// row-vector times 4x4 matrix (matrix loaded row-major via 4x float4)
__device__ __forceinline__ float4 rowMat(const float4 f, const float* __restrict__ B) {
    const float4* q = reinterpret_cast<const float4*>(B);
    float4 b0 = q[0], b1 = q[1], b2 = q[2], b3 = q[3];
    float4 o;
    o.x = f.x*b0.x + f.y*b1.x + f.z*b2.x + f.w*b3.x;
    o.y = f.x*b0.y + f.y*b1.y + f.z*b2.y + f.w*b3.y;
    o.z = f.x*b0.z + f.y*b1.z + f.z*b2.z + f.w*b3.z;
    o.w = f.x*b0.w + f.y*b1.w + f.z*b2.w + f.w*b3.w;
    return o;
}

// post-multiply row by rotX: cols 1,2 mix
__device__ __forceinline__ void rotXrow(float4& v, float c, float s) {
    float v1 = v.y, v2 = v.z;
    v.y = c*v1 + s*v2;
    v.z = c*v2 - s*v1;
}

// post-multiply row by rotZ: cols 0,1 mix
__device__ __forceinline__ void rotZrow(float4& v, float c, float s) {
    float v0 = v.x, v1 = v.y;
    v.x = c*v0 + s*v1;
    v.y = c*v1 - s*v0;
}

// post-multiply row by homogeneous rotation (3x3 G, col3=(0,0,0,1) row3=0):
// out.xyz = f.x*G[0] + f.y*G[1] + f.z*G[2]; out.w = f.w.  (i==3 row passes through)
__device__ __forceinline__ float4 applyG(const float4 f, const float G[3][3]) {
    float4 o;
    o.x = f.x*G[0][0] + f.y*G[1][0] + f.z*G[2][0];
    o.y = f.x*G[0][1] + f.y*G[1][1] + f.z*G[2][1];
    o.z = f.x*G[0][2] + f.y*G[1][2] + f.z*G[2][2];
    o.w = f.w;
    return o;
}

__device__ __forceinline__ void rotAxis3(float G[3][3], float c, float s,
                                         float u0, float u1, float u2) {
    float omc = 1.0f - c;
    G[0][0] = c + u0*u0*omc;    G[0][1] = u0*u1*omc - u2*s; G[0][2] = u0*u2*omc + u1*s;
    G[1][0] = u0*u1*omc + u2*s; G[1][1] = c + u1*u1*omc;    G[1][2] = u1*u2*omc - u0*s;
    G[2][0] = u0*u2*omc - u1*s; G[2][1] = u1*u2*omc + u0*s; G[2][2] = c + u2*u2*omc;
}

// ---------------------------- fused kernel ----------------------------
// 256 threads = 4 waves. Each wave owns 16 residues; each residue owned by
// 4 lanes (lane i = matrix row i). Every frame obeys F_next = F_prev @ M,
// which is row-decomposable, so each lane carries one float4 row through
// the whole chain. All lanes run identical code (row 3 starts at (0,0,0,1)
// and follows the same recurrence). Prefix quantities (Gram-Schmidt, axes,
// angle norms) are computed redundantly by the 4 lanes. Frames are written
// to LDS (atom gather is same-wave -> NO __syncthreads needed) and to
// global from registers. Atom phase: 576 atoms per wave = 9*64.

__global__ __launch_bounds__(256, 2) void fused_kernel(
    const int*   __restrict__ seq,     // (BL)
    const float* __restrict__ xyz,     // (BL,3,3)
    const float* __restrict__ alphas,  // (BL,10,2)
    const int*   __restrict__ bidx,    // (NAA,36)
    const float* __restrict__ RTs,     // (NAA,7,4,4)
    const float* __restrict__ xibf,    // (NAA,36,4)
    float*       __restrict__ out_fr,  // (BL,9,4,4)
    float*       __restrict__ out_xyz, // (BL,36,3)
    int BL)
{
    __shared__ __align__(16) float lds_fr[RPB * RSS];   // 46.1 KB
    __shared__ int lds_seq[RPB];

    const int tid   = threadIdx.x;
    const int lane  = tid & 63;
    const int wv    = tid >> 6;
    const int i     = lane & 3;          // row index 0..3
    const int res   = wv*16 + (lane >> 2);  // residue within block 0..63
    const int base  = blockIdx.x * RPB;
    const int t     = base + res;
    const bool valid = (t < BL);

    float* fl = lds_fr + res * RSS;
    float* fg = out_fr + (size_t)t * 144;

    if (valid) {
        int s = seq[t];
        if (i == 0) lds_seq[res] = s;
        const float* rb = RTs + (size_t)s * 112;
        const float* al = alphas + (size_t)t * 20;

        // ---- Gram-Schmidt (redundant across the 4 lanes of a residue) ----
        const float* p = xyz + (size_t)t * 9;
        float N0=p[0], N1=p[1], N2=p[2];
        float A0=p[3], A1=p[4], A2=p[5];
        float C0=p[6], C1=p[7], C2=p[8];
        float v10=C0-A0, v11=C1-A1, v12=C2-A2;
        float v20=N0-A0, v21=N1-A1, v22=N2-A2;
        float i1 = rsqz(v10*v10 + v11*v11 + v12*v12);
        float e10=v10*i1, e11=v11*i1, e12=v12*i1;
        float d  = e10*v20 + e11*v21 + e12*v22;
        float u20=v20-e10*d, u21=v21-e11*d, u22=v22-e12*d;
        float i2 = rsqz(u20*u20 + u21*u21 + u22*u22);
        float e20=u20*i2, e21=u21*i2, e22=u22*i2;
        float e30=e11*e22 - e12*e21;
        float e31=e12*e20 - e10*e22;
        float e32=e10*e21 - e11*e20;

        // my row of F0 (row 3 = 0,0,0,1)
        bool s0 = (i==0), s1 = (i==1), s2 = (i==2);
        float4 f0r;
        f0r.x = s0?e10 : s1?e11 : s2?e12 : 0.f;
        f0r.y = s0?e20 : s1?e21 : s2?e22 : 0.f;
        f0r.z = s0?e30 : s1?e31 : s2?e32 : 0.f;
        f0r.w = s0?A0  : s1?A1  : s2?A2  : 1.f;

        *reinterpret_cast<float4*>(fl + i*4) = f0r;
        *reinterpret_cast<float4*>(fg + i*4) = f0r;

        // ---- angles (10 pairs, redundant) ----
        const float4* a4p = reinterpret_cast<const float4*>(al);
        float4 q0 = a4p[0], q1 = a4p[1], q2 = a4p[2], q3 = a4p[3], q4 = a4p[4];
        float ca0,sa0, ca1,sa1, ca2,sa2, ca3,sa3, ca4,sa4;
        float ca5,sa5, ca6,sa6, ca7,sa7, ca8,sa8, ca9,sa9;
        angNorm(q0.x,q0.y, ca0,sa0);  angNorm(q0.z,q0.w, ca1,sa1);
        angNorm(q1.x,q1.y, ca2,sa2);  angNorm(q1.z,q1.w, ca3,sa3);
        angNorm(q2.x,q2.y, ca4,sa4);  angNorm(q2.z,q2.w, ca5,sa5);
        angNorm(q3.x,q3.y, ca6,sa6);  angNorm(q3.z,q3.w, ca7,sa7);
        angNorm(q4.x,q4.y, ca8,sa8);  angNorm(q4.z,q4.w, ca9,sa9);

        // ---- F1..F3 = (F0 @ B_k) @ rotX(a_k), row-wise ----
        float4 rw;
        rw = rowMat(f0r, rb +  0); rotXrow(rw, ca0, sa0);
        *reinterpret_cast<float4*>(fl + 1*FRS + i*4) = rw;
        *reinterpret_cast<float4*>(fg + 16 + i*4) = rw;
        rw = rowMat(f0r, rb + 16); rotXrow(rw, ca1, sa1);
        *reinterpret_cast<float4*>(fl + 2*FRS + i*4) = rw;
        *reinterpret_cast<float4*>(fg + 32 + i*4) = rw;
        rw = rowMat(f0r, rb + 32); rotXrow(rw, ca2, sa2);
        *reinterpret_cast<float4*>(fl + 3*FRS + i*4) = rw;
        *reinterpret_cast<float4*>(fg + 48 + i*4) = rw;

        // ---- CB axes from base geometry (redundant) ----
        const float* bxp = xibf + (size_t)s * 144;
        float4 b0 = reinterpret_cast<const float4*>(bxp)[0];
        float4 b1 = reinterpret_cast<const float4*>(bxp)[1];
        float4 b2 = reinterpret_cast<const float4*>(bxp)[2];
        float4 b4 = reinterpret_cast<const float4*>(bxp)[4];

        float NCr0 = 0.5f*(b2.x + b0.x), NCr1 = 0.5f*(b2.y + b0.y), NCr2 = 0.5f*(b2.z + b0.z);
        float ba0 = b4.x - b1.x, ba1 = b4.y - b1.y, ba2 = b4.z - b1.z;
        float w0 = NCr0 - b1.x, w1 = NCr1 - b1.y, w2 = NCr2 - b1.z;
        float x10 = ba1*w2 - ba2*w1, x11 = ba2*w0 - ba0*w2, x12 = ba0*w1 - ba1*w0;
        float in1 = rsqz(x10*x10 + x11*x11 + x12*x12);
        x10 *= in1; x11 *= in1; x12 *= in1;
        float NCp0 = b2.x - b0.x, NCp1 = b2.y - b0.y, NCp2 = b2.z - b0.z;
        float dp = NCp0*NCr0 + NCp1*NCr1 + NCp2*NCr2;
        float dr = NCr0*NCr0 + NCr1*NCr1 + NCr2*NCr2;
        float sf = dp / dr;
        float g0 = NCp0 - sf*NCr0, g1 = NCp1 - sf*NCr1, g2 = NCp2 - sf*NCr2;
        float x20 = ba1*g2 - ba2*g1, x21 = ba2*g0 - ba0*g2, x22 = ba0*g1 - ba1*g0;
        float in2 = rsqz(x20*x20 + x21*x21 + x22*x22);
        x20 *= in2; x21 *= in2; x22 *= in2;

        float G1[3][3], G2[3][3];
        rotAxis3(G1, ca7, sa7, x10, x11, x12);
        rotAxis3(G2, ca8, sa8, x20, x21, x22);

        // ---- F8 = (F0 @ G1h) @ G2h, row-wise ----
        float4 f8r = applyG(applyG(f0r, G1), G2);
        *reinterpret_cast<float4*>(fl + 8*FRS + i*4) = f8r;
        *reinterpret_cast<float4*>(fg + 128 + i*4) = f8r;

        // ---- suffix chain F4..F7, row-wise ----
        rw = rowMat(f8r, rb + 48); rotXrow(rw, ca3, sa3); rotZrow(rw, ca9, sa9);
        *reinterpret_cast<float4*>(fl + 4*FRS + i*4) = rw;
        *reinterpret_cast<float4*>(fg + 64 + i*4) = rw;
        rw = rowMat(rw, rb + 64); rotXrow(rw, ca4, sa4);
        *reinterpret_cast<float4*>(fl + 5*FRS + i*4) = rw;
        *reinterpret_cast<float4*>(fg + 80 + i*4) = rw;
        rw = rowMat(rw, rb + 80); rotXrow(rw, ca5, sa5);
        *reinterpret_cast<float4*>(fl + 6*FRS + i*4) = rw;
        *reinterpret_cast<float4*>(fg + 96 + i*4) = rw;
        rw = rowMat(rw, rb + 96); rotXrow(rw, ca6, sa6);
        *reinterpret_cast<float4*>(fl + 7*FRS + i*4) = rw;
        *reinterpret_cast<float4*>(fg + 112 + i*4) = rw;
    }

    // ---- atom phase: same wave that produced the frames (no __syncthreads).
    // Intra-wave LDS write->read ordering is enforced by lgkmcnt waits the
    // compiler inserts (it cannot disprove aliasing on lds_fr).
    const int wbase = wv * 16;
#pragma unroll
    for (int k = 0; k < 9; ++k) {
        int c = k*64 + lane;              // 0..575 within this wave
        int lres = c / 36;
        int a = c - lres*36;
        int res2 = wbase + lres;
        int tt = base + res2;
        if (tt < BL) {
            int ss  = lds_seq[res2];
            int idx = bidx[ss*36 + a];
            float4 v = *reinterpret_cast<const float4*>(xibf + ((size_t)ss*36 + a)*4);
            const float* fp = lds_fr + res2*RSS + idx*FRS;
            float4 r0 = *reinterpret_cast<const float4*>(fp);
            float4 r1 = *reinterpret_cast<const float4*>(fp + 4);
            float4 r2 = *reinterpret_cast<const float4*>(fp + 8);
            size_t o = ((size_t)(base + wbase)*36 + c)*3;   // == (tt*36+a)*3, dense in c
            out_xyz[o+0] = r0.x*v.x + r0.y*v.y + r0.z*v.z + r0.w*v.w;
            out_xyz[o+1] = r1.x*v.x + r1.y*v.y + r1.z*v.z + r1.w*v.w;
            out_xyz[o+2] = r2.x*v.x + r2.y*v.y + r2.z*v.z + r2.w*v.w;
        }
    }
}

// ---------------------------- launch ----------------------------

extern "C" void kernel_launch(void* const* d_in, const int* in_sizes, int n_in,
                              void* d_out, int out_size, void* d_ws, size_t ws_size,
                              hipStream_t stream) {
    const int*   seq    = (const int*)  d_in[0];
    const float* xyz    = (const float*)d_in[1];
    const float* alphas = (const float*)d_in[2];
    const int*   bidx   = (const int*)  d_in[3];
    const float* RTs    = (const float*)d_in[4];
    const float* xibf   = (const float*)d_in[5];
    float*       out    = (float*)d_out;

    int BL = in_sizes[0];                       // B * L
    float* out_xyz = out + (size_t)BL * 144;

    int blocks = (BL + RPB - 1) / RPB;
    fused_kernel<<<blocks, 256, 0, stream>>>(seq, xyz, alphas, bidx, RTs, xibf,
                                             out, out_xyz, BL);
}